// Round 1
// baseline (115.411 us; speedup 1.0000x reference)
//
#include <hip/hip_runtime.h>

#define L 21
#define C0 32
#define C1 32
#define IN_DIM 7
#define GHIST 256
#define PAD 64

// ---------------- K1: per-block histogram of idx ----------------
__global__ __launch_bounds__(256) void k_hist(const int* __restrict__ idx, int E,
                                              int* __restrict__ blockCounts) {
  __shared__ int h[L];
  int tid = threadIdx.x;
  if (tid < L) h[tid] = 0;
  __syncthreads();
  int per = (E + GHIST - 1) / GHIST;
  int s = blockIdx.x * per;
  int e = min(E, s + per);
  for (int i = s + tid; i < e; i += blockDim.x)
    atomicAdd(&h[idx[i]], 1);
  __syncthreads();
  if (tid < L) blockCounts[blockIdx.x * L + tid] = h[tid];
}

// ---------------- K2: scan, padded bases, per-block cursors, waveL, pad perm ---
__global__ __launch_bounds__(256) void k_scan(const int* __restrict__ blockCounts,
                                              int* __restrict__ cursor,
                                              int* __restrict__ perm,
                                              int* __restrict__ waveL,
                                              int Wmax) {
  __shared__ int tot[L];
  __shared__ int base[L + 1];
  int tid = threadIdx.x;
  if (tid < L) {
    int s = 0;
#pragma unroll 8
    for (int b = 0; b < GHIST; b++) s += blockCounts[b * L + tid];
    tot[tid] = s;
  }
  __syncthreads();
  if (tid == 0) {
    int a = 0;
    for (int l = 0; l < L; l++) { base[l] = a; a += (tot[l] + PAD - 1) & ~(PAD - 1); }
    base[L] = a;
  }
  __syncthreads();
  if (tid < L) {
    int a = base[tid];
#pragma unroll 8
    for (int b = 0; b < GHIST; b++) {
      cursor[b * L + tid] = a;
      a += blockCounts[b * L + tid];
    }
  }
  // fill padding slots of perm with -1
  for (int l = 0; l < L; l++) {
    int s = base[l] + tot[l];
    int e = base[l + 1];
    for (int i = s + tid; i < e; i += blockDim.x) perm[i] = -1;
  }
  __syncthreads();
  int W = base[L] >> 6;  // number of real waves
  for (int w = tid; w < Wmax; w += blockDim.x) {
    int lv = -1;
    if (w < W) {
      int pos = w << 6;
      for (int l = 0; l < L; l++)
        if (pos >= base[l] && pos < base[l + 1]) lv = l;
    }
    waveL[w] = lv;
  }
}

// ---------------- K3: scatter edge ids into bucketed perm ----------------
__global__ __launch_bounds__(256) void k_scatter(const int* __restrict__ idx, int E,
                                                 const int* __restrict__ cursor,
                                                 int* __restrict__ perm) {
  __shared__ int cur[L];
  int tid = threadIdx.x;
  if (tid < L) cur[tid] = cursor[blockIdx.x * L + tid];
  __syncthreads();
  int per = (E + GHIST - 1) / GHIST;
  int s = blockIdx.x * per;
  int e = min(E, s + per);
  for (int i = s + tid; i < e; i += blockDim.x) {
    int l = idx[i];
    int pos = atomicAdd(&cur[l], 1);
    perm[pos] = i;
  }
}

// ---------------- K4: compute. One thread per (bucketed) edge; wave-uniform l ---
__global__ __launch_bounds__(256) void k_compute(const float* __restrict__ inp,
                                                 const float* __restrict__ W0g,
                                                 const float* __restrict__ b0g,
                                                 const float* __restrict__ W1g,
                                                 const float* __restrict__ b1g,
                                                 const int* __restrict__ perm,
                                                 const int* __restrict__ waveL,
                                                 float* __restrict__ out,
                                                 int Wmax) {
  int gid = blockIdx.x * blockDim.x + threadIdx.x;
  int wave = gid >> 6;
  if (wave >= Wmax) return;
  int l = waveL[wave];
  if (l < 0) return;                       // wave entirely past data (uniform)
  l = __builtin_amdgcn_readfirstlane(l);   // force SGPR -> scalar weight loads

  int p = perm[gid];
  bool valid = p >= 0;
  int pp = valid ? p : 0;

  const float* xrow = inp + pp * IN_DIM;
  float x[IN_DIM];
#pragma unroll
  for (int k = 0; k < IN_DIM; k++) x[k] = xrow[k];

  const float* w0 = W0g + l * (IN_DIM * C0);
  const float* B0 = b0g + l * C0;
  const float* w1 = W1g + l * (C0 * C1);
  const float* B1 = b1g + l * C1;

  float h[C0];
#pragma unroll
  for (int c = 0; c < C0; c++) h[c] = B0[c];
#pragma unroll
  for (int k = 0; k < IN_DIM; k++) {
#pragma unroll
    for (int c = 0; c < C0; c++) h[c] = fmaf(x[k], w0[k * C0 + c], h[c]);
  }
#pragma unroll
  for (int c = 0; c < C0; c++) h[c] = h[c] >= 0.f ? h[c] : 0.2f * h[c];

  float* orow = out + (size_t)pp * C1;
#pragma unroll
  for (int j = 0; j < 4; j++) {
    float acc[8];
#pragma unroll
    for (int i = 0; i < 8; i++) acc[i] = B1[j * 8 + i];
#pragma unroll
    for (int k = 0; k < C0; k++) {
#pragma unroll
      for (int i = 0; i < 8; i++) acc[i] = fmaf(h[k], w1[k * C1 + j * 8 + i], acc[i]);
    }
#pragma unroll
    for (int i = 0; i < 8; i++) acc[i] = acc[i] >= 0.f ? acc[i] : 0.2f * acc[i];
    if (valid) {
      float4 v0 = {acc[0], acc[1], acc[2], acc[3]};
      float4 v1 = {acc[4], acc[5], acc[6], acc[7]};
      *(float4*)(orow + j * 8) = v0;
      *(float4*)(orow + j * 8 + 4) = v1;
    }
  }
}

extern "C" void kernel_launch(void* const* d_in, const int* in_sizes, int n_in,
                              void* d_out, int out_size, void* d_ws, size_t ws_size,
                              hipStream_t stream) {
  const float* inp = (const float*)d_in[0];
  const int* idx   = (const int*)d_in[1];
  const float* W0  = (const float*)d_in[2];
  const float* b0  = (const float*)d_in[3];
  const float* W1  = (const float*)d_in[4];
  const float* b1  = (const float*)d_in[5];
  float* out = (float*)d_out;
  int E = in_sizes[1];

  int Wmax = (E + L * PAD + 63) >> 6;  // upper bound on padded wave count

  int* ws = (int*)d_ws;
  int* blockCounts = ws;                       // GHIST*L
  int* cursor      = blockCounts + GHIST * L;  // GHIST*L
  int* waveL       = cursor + GHIST * L;       // Wmax
  int* perm        = waveL + Wmax;             // E + L*PAD

  k_hist<<<GHIST, 256, 0, stream>>>(idx, E, blockCounts);
  k_scan<<<1, 256, 0, stream>>>(blockCounts, cursor, perm, waveL, Wmax);
  k_scatter<<<GHIST, 256, 0, stream>>>(idx, E, cursor, perm);

  int threads = Wmax * 64;
  k_compute<<<(threads + 255) / 256, 256, 0, stream>>>(inp, W0, b0, W1, b1,
                                                       perm, waveL, out, Wmax);
}